// Round 1
// 441.869 us; speedup vs baseline: 1.0362x; 1.0362x over previous
//
#include <hip/hip_runtime.h>

// Problem constants
#define DM   1024
#define MR   8192          // L*B rows
#define LKK  1025
#define OUTOFF 8388608     // MR*DM floats, start of attn region in d_out
#define VPADF 24           // front pad rows of vbuf (covers shift -3..-1)

#define GB 512             // gemm compute blocks (64 m-tiles x 8 n-tiles)
#define FB 1024            // fill blocks appended to each gemm grid
#define SCR4 2366464       // scratch bytes/16: (vbuf+valb+Wvb+Wob)=37,863,424 B
#define MID4 9580032       // SCR4 + (END4-SCR4)/2
#define END4 16793600      // attn total float4

typedef short bf16x8 __attribute__((ext_vector_type(8)));
typedef float f32x4  __attribute__((ext_vector_type(4)));
typedef unsigned short u16;
typedef u16 u16x8 __attribute__((ext_vector_type(8)));

__device__ __forceinline__ u16 f2bf(float f) {
  union { float f; unsigned u; } v; v.f = f;
  return (u16)((v.u + 0x7fffu + ((v.u >> 16) & 1u)) >> 16);  // RNE
}

__device__ __forceinline__ void gl_lds16(const u16* g, u16* l) {
  __builtin_amdgcn_global_load_lds((const __attribute__((address_space(1))) void*)g,
                                   (__attribute__((address_space(3))) void*)l,
                                   16, 0, 0);
}

// attn flat layout: [hb(64)][l(1024)][t(1025)]. One float4 of {0,1}.
__device__ __forceinline__ f32x4 onehot4(int i) {
  unsigned xf = (unsigned)i << 2;                       // linear float index
  unsigned row0 = (unsigned)(((unsigned long long)xf * 4290777085ULL) >> 42);
  int t0 = (int)(xf - row0 * 1025u);
  f32x4 v;
#pragma unroll
  for (int c = 0; c < 4; c++) {
    int tc = t0 + c;
    unsigned rc = row0 + ((tc >= 1025) ? 1u : 0u);
    tc -= (tc >= 1025) ? 1025 : 0;
    int h = (int)(rc >> 13);
    int l = (int)(rc & 1023u);
    int j = l + h - 3;
    int hot = ((unsigned)j <= 1024u) ? j : 1024;
    v[c] = (tc == hot) ? 1.0f : 0.0f;
  }
  return v;
}

// XCD-friendly tile mapping for 512 blocks (64 m-tiles x 8 n-tiles)
__device__ __forceinline__ void tile_of(int b, int& m0, int& n0) {
  int mt = (b & 7) * 8 + ((b >> 3) & 7);
  int nt = b >> 6;
  m0 = mt * 128; n0 = nt * 128;
}

// Convert value/Wv/Wo f32->bf16 and zero vbuf pad rows. 8 elems/thread.
__global__ __launch_bounds__(256) void convert_k(const float* __restrict__ value,
                                                 const float* __restrict__ Wv,
                                                 const float* __restrict__ Wo,
                                                 u16* __restrict__ valb,
                                                 u16* __restrict__ Wvb,
                                                 u16* __restrict__ Wob,
                                                 u16* __restrict__ vbuf) {
  size_t c = (size_t)blockIdx.x * 256 + threadIdx.x;
  const size_t C1 = 1048576;            // value: 8388608/8
  const size_t C2 = C1 + 131072;        // + Wv
  const size_t C3 = C2 + 131072;        // + Wo = 1310720
  const size_t C4 = C3 + 7168;          // + pad rows (24+32 rows)
  if (c < C3) {
    const float* s; u16* d; size_t off;
    if (c < C1)      { s = value; d = valb; off = c * 8; }
    else if (c < C2) { s = Wv;    d = Wvb;  off = (c - C1) * 8; }
    else             { s = Wo;    d = Wob;  off = (c - C2) * 8; }
    float4 a = *(const float4*)(s + off);
    float4 b = *(const float4*)(s + off + 4);
    u16x8 p;
    p[0]=f2bf(a.x); p[1]=f2bf(a.y); p[2]=f2bf(a.z); p[3]=f2bf(a.w);
    p[4]=f2bf(b.x); p[5]=f2bf(b.y); p[6]=f2bf(b.z); p[7]=f2bf(b.w);
    *(u16x8*)(d + off) = p;
  } else if (c < C4) {
    size_t j = c - C3;
    u16x8 z = {0,0,0,0,0,0,0,0};
    if (j < 3072) *(u16x8*)(vbuf + j * 8) = z;                              // front 24 rows
    else *(u16x8*)(vbuf + (size_t)8216 * DM + (j - 3072) * 8) = z;          // back 32 rows
  }
}

// Shared K-loop body: read frags from ring buffer at rO, 8 MFMA.
// LDS frag layout per 128x32 tile: addr(row,kq)=(row>>4)*512+(row&15)*32+kq*8
// -> each wave's 64 lanes read one contiguous 1KB block (conflict-free).
#define GEMM_COMPUTE \
  { bf16x8 af[4], bf[2]; \
    _Pragma("unroll") for (int i2 = 0; i2 < 4; i2++) \
      af[i2] = *(const bf16x8*)(smem + rO + ((wm + i2*16) >> 4) * 512 + lr*32 + kq8); \
    _Pragma("unroll") for (int j2 = 0; j2 < 2; j2++) \
      bf[j2] = *(const bf16x8*)(smem + rO + 4096 + ((wn + j2*16) >> 4) * 512 + lr*32 + kq8); \
    _Pragma("unroll") for (int i2 = 0; i2 < 4; i2++) \
      _Pragma("unroll") for (int j2 = 0; j2 < 2; j2++) \
        acc[i2][j2] = __builtin_amdgcn_mfma_f32_16x16x32_bf16(af[i2], bf[j2], acc[i2][j2], 0, 0, 0); }

#define PIPE_WAIT2 \
  asm volatile("s_waitcnt vmcnt(2)" ::: "memory"); \
  __builtin_amdgcn_s_barrier(); \
  __builtin_amdgcn_sched_barrier(0);

#define PIPE_WAIT0 \
  asm volatile("s_waitcnt vmcnt(0)" ::: "memory"); \
  __builtin_amdgcn_s_barrier(); \
  __builtin_amdgcn_sched_barrier(0);

#define PIPE_ROT { int tmp = rO; rO = pO; pO = sO; sO = tmp; }

// GEMM1: vproj[m][n] = sum_k valb[m][k]*Wvb[n][k] + bv[n] -> bf16 rows +VPADF.
// 3-buffer LDS ring, depth-2 counted-vmcnt pipeline (T3/T4): stage loads for
// tile t+2 stay in flight across the per-iter barrier; vmcnt(2) waits only the
// pair for the tile about to be consumed. Safety: each wave drains its own
// stage pair before the barrier (cross-wave LDS visibility); the stage target
// buffer's last readers finished (lgkm-drained into MFMAs) before the previous
// barrier. Blocks >= GB: grid-stride nontemporal fill of attn[SCR4,MID4).
__global__ __launch_bounds__(512, 6) void gemm1_k(const u16* __restrict__ valb,
                                                  const u16* __restrict__ Wvb,
                                                  const float* __restrict__ bv,
                                                  u16* __restrict__ vbuf,
                                                  f32x4* __restrict__ attn4) {
  __shared__ __align__(16) u16 smem[24576];   // 48 KB: 3 x (A 8KB + B 8KB); epilogue reuses 33 KB
  if (blockIdx.x >= GB) {
    int i = SCR4 + (blockIdx.x - GB) * 512 + (int)threadIdx.x;
    const int stride = FB * 512;
    for (; i < MID4; i += stride)
      __builtin_nontemporal_store(onehot4(i), attn4 + i);
    return;
  }
  int m0, n0; tile_of(blockIdx.x, m0, n0);
  int t = threadIdx.x, lane = t & 63, wave = t >> 6;
  int wm = (wave >> 2) * 64, wn = (wave & 3) * 32;
  int srow = wave * 16 + (lane >> 2);         // staging row 0..127
  int ko = (lane & 3) * 8;                    // staging k offset
  int ldso = wave * 512;                      // staging LDS base (wave-uniform)
  int lr = lane & 15, kq8 = (lane >> 4) * 8;  // frag indices
  f32x4 z = {0.f, 0.f, 0.f, 0.f};
  f32x4 acc[4][2];
#pragma unroll
  for (int i = 0; i < 4; i++)
#pragma unroll
    for (int j = 0; j < 2; j++) acc[i][j] = z;

  const u16* Ab = valb + (size_t)(m0 + srow) * DM + ko;
  const u16* Bb = Wvb + (size_t)(n0 + srow) * DM + ko;
  // prologue: stage tiles 0 and 1
  gl_lds16(Ab,      smem + ldso);
  gl_lds16(Bb,      smem + 4096 + ldso);
  gl_lds16(Ab + 32, smem + 8192 + ldso);
  gl_lds16(Bb + 32, smem + 8192 + 4096 + ldso);
  int rO = 0, pO = 8192, sO = 16384;
  for (int kt = 0; kt < 30; ++kt) {
    PIPE_WAIT2;
    int kk = (kt + 2) * 32;
    gl_lds16(Ab + kk, smem + sO + ldso);
    gl_lds16(Bb + kk, smem + sO + 4096 + ldso);
    GEMM_COMPUTE;
    PIPE_ROT;
  }
  PIPE_WAIT2;
  GEMM_COMPUTE;
  PIPE_ROT;
  PIPE_WAIT0;
  GEMM_COMPUTE;
  __syncthreads();

  // scatter acc -> LDS (bf16, padded stride 132), then coalesced global stores
  int q = lane >> 4, col = lane & 15;
#pragma unroll
  for (int j = 0; j < 2; j++) {
    int nl = wn + j * 16 + col;
    float bvn = bv[n0 + nl];
#pragma unroll
    for (int i = 0; i < 4; i++) {
      int ml = wm + i * 16 + q * 4;
#pragma unroll
      for (int r = 0; r < 4; r++)
        smem[(ml + r) * 132 + nl] = f2bf(acc[i][j][r] + bvn);
    }
  }
  __syncthreads();
  int cc = (t & 15) * 8;
  int rbase = (t >> 4) * 4;
#pragma unroll
  for (int s = 0; s < 4; s++) {
    int row = rbase + s;
    u16x8 v = *(const u16x8*)(smem + row * 132 + cc);
    *(u16x8*)(vbuf + (size_t)(m0 + row + VPADF) * DM + n0 + cc) = v;
  }
}

// GEMM2: x[m][n] = sum_k gather(vproj)[m][k]*Wob[n][k] + bo[n] + query[m][n]
// gather = per-head row shift (h-3)*8, absorbed into A base via vbuf pad rows.
// Same counted-vmcnt ring pipeline. Blocks >= GB: fill attn[MID4,END4).
__global__ __launch_bounds__(512, 6) void gemm2_k(const u16* __restrict__ vbuf,
                                                  const u16* __restrict__ Wob,
                                                  const float* __restrict__ bo,
                                                  const float* __restrict__ query,
                                                  float* __restrict__ xo,
                                                  f32x4* __restrict__ attn4) {
  __shared__ __align__(16) u16 smem[24576];   // 48 KB: 3 x (A 8KB + B 8KB)
  if (blockIdx.x >= GB) {
    int i = MID4 + (blockIdx.x - GB) * 512 + (int)threadIdx.x;
    const int stride = FB * 512;
    for (; i < END4; i += stride)
      __builtin_nontemporal_store(onehot4(i), attn4 + i);
    return;
  }
  int m0, n0; tile_of(blockIdx.x, m0, n0);
  int t = threadIdx.x, lane = t & 63, wave = t >> 6;
  int wm = (wave >> 2) * 64, wn = (wave & 3) * 32;
  int srow = wave * 16 + (lane >> 2);
  int ko = (lane & 3) * 8;
  int ldso = wave * 512;
  int lr = lane & 15, kq8 = (lane >> 4) * 8;
  f32x4 z = {0.f, 0.f, 0.f, 0.f};
  f32x4 acc[4][2];
#pragma unroll
  for (int i = 0; i < 4; i++)
#pragma unroll
    for (int j = 0; j < 2; j++) acc[i][j] = z;

  const u16* Ab = vbuf + (size_t)(m0 + srow + VPADF) * DM + ko;
  const u16* Bb = Wob + (size_t)(n0 + srow) * DM + ko;
  // A source for k-block kb (kb*32 = k0): head h = kb>>2, row shift (h-3)*8
  // prologue: kb = 0,1 (both head 0 -> shift -24 rows; pad rows are zeroed)
  gl_lds16(Ab + (ptrdiff_t)(-24) * DM,      smem + ldso);
  gl_lds16(Bb,                              smem + 4096 + ldso);
  gl_lds16(Ab + (ptrdiff_t)(-24) * DM + 32, smem + 8192 + ldso);
  gl_lds16(Bb + 32,                         smem + 8192 + 4096 + ldso);
  int rO = 0, pO = 8192, sO = 16384;
  for (int kt = 0; kt < 30; ++kt) {
    PIPE_WAIT2;
    int kb = kt + 2;
    ptrdiff_t ao = (ptrdiff_t)(((kb >> 2) - 3) * 8) * DM + kb * 32;
    gl_lds16(Ab + ao,      smem + sO + ldso);
    gl_lds16(Bb + kb * 32, smem + sO + 4096 + ldso);
    GEMM_COMPUTE;
    PIPE_ROT;
  }
  PIPE_WAIT2;
  GEMM_COMPUTE;
  PIPE_ROT;
  PIPE_WAIT0;
  GEMM_COMPUTE;

  int q = lane >> 4, col = lane & 15;
#pragma unroll
  for (int j = 0; j < 2; j++) {
    int n = n0 + wn + j * 16 + col;
    float bon = bo[n];
#pragma unroll
    for (int i = 0; i < 4; i++) {
      int mb = m0 + wm + i * 16 + q * 4;
#pragma unroll
      for (int r = 0; r < 4; r++) {
        size_t idx = (size_t)(mb + r) * DM + n;
        xo[idx] = acc[i][j][r] + bon + query[idx];
      }
    }
  }
}

// Fused LayerNorm + scratch-region attn fill.
// Blocks 0..2047: in-place LN over rows of x (one wave per row).
// Blocks 2048..3071: fill attn[0,SCR4) (the scratch region, now dead).
__global__ __launch_bounds__(256) void lnfill_k(float* __restrict__ x,
                                                const float* __restrict__ gamma,
                                                const float* __restrict__ beta,
                                                f32x4* __restrict__ attn4) {
  int blk = blockIdx.x;
  if (blk < 2048) {
    int lane = threadIdx.x & 63, wave = threadIdx.x >> 6;
    size_t row = (size_t)blk * 4 + wave;
    float4* p = (float4*)(x + row * DM);
    float4 v[4];
    float s = 0.f, ss = 0.f;
#pragma unroll
    for (int i = 0; i < 4; i++) {
      v[i] = p[i * 64 + lane];
      s  += v[i].x + v[i].y + v[i].z + v[i].w;
      ss += v[i].x * v[i].x + v[i].y * v[i].y + v[i].z * v[i].z + v[i].w * v[i].w;
    }
#pragma unroll
    for (int o = 32; o > 0; o >>= 1) {
      s  += __shfl_xor(s, o);
      ss += __shfl_xor(ss, o);
    }
    float mu = s * (1.0f / 1024.0f);
    float var = ss * (1.0f / 1024.0f) - mu * mu;
    float rstd = rsqrtf(var + 1e-5f);
    const float4* g4 = (const float4*)gamma;
    const float4* b4 = (const float4*)beta;
#pragma unroll
    for (int i = 0; i < 4; i++) {
      float4 g = g4[i * 64 + lane], bb = b4[i * 64 + lane];
      float4 o;
      o.x = (v[i].x - mu) * rstd * g.x + bb.x;
      o.y = (v[i].y - mu) * rstd * g.y + bb.y;
      o.z = (v[i].z - mu) * rstd * g.z + bb.z;
      o.w = (v[i].w - mu) * rstd * g.w + bb.w;
      p[i * 64 + lane] = o;
    }
  } else {
    int i = (blk - 2048) * 256 + (int)threadIdx.x;
    const int stride = 1024 * 256;
    for (; i < SCR4; i += stride)
      __builtin_nontemporal_store(onehot4(i), attn4 + i);
  }
}

extern "C" void kernel_launch(void* const* d_in, const int* in_sizes, int n_in,
                              void* d_out, int out_size, void* d_ws, size_t ws_size,
                              hipStream_t stream) {
  const float* query = (const float*)d_in[0];
  // d_in[1] key, d_in[3..6] Wq/bq/Wk/bk: dead code (scores overwritten by bias)
  const float* value = (const float*)d_in[2];
  const float* Wv    = (const float*)d_in[7];
  const float* bv    = (const float*)d_in[8];
  const float* Wo    = (const float*)d_in[9];
  const float* bo    = (const float*)d_in[10];
  const float* gamma = (const float*)d_in[11];
  const float* beta  = (const float*)d_in[12];

  float* out  = (float*)d_out;
  float* attn = out + OUTOFF;
  // Scratch lives inside the attn region (268.7 MB). The attn fill is split:
  // non-scratch range [SCR4,END4) rides along with the GEMMs (overlap);
  // scratch range [0,SCR4) is filled last (after gemm2 consumed vbuf).
  char* scr = (char*)attn;
  u16* vbuf = (u16*)scr;                              // 8248*1024*2 = 16,891,904 B
  u16* valb = (u16*)(scr + 16891904);                 // 16,777,216 B
  u16* Wvb  = (u16*)(scr + 33669120);                 //  2,097,152 B
  u16* Wob  = (u16*)(scr + 35766272);                 //  2,097,152 B

  convert_k<<<5148, 256, 0, stream>>>(value, Wv, Wo, valb, Wvb, Wob, vbuf);
  gemm1_k<<<GB + FB, 512, 0, stream>>>(valb, Wvb, bv, vbuf, (f32x4*)attn);
  gemm2_k<<<GB + FB, 512, 0, stream>>>(vbuf, Wob, bo, query, out, (f32x4*)attn);
  lnfill_k<<<3072, 256, 0, stream>>>(out, gamma, beta, (f32x4*)attn);
}

// Round 2
// 427.676 us; speedup vs baseline: 1.0706x; 1.0332x over previous
//
#include <hip/hip_runtime.h>

// Problem constants
#define DM   1024
#define MR   8192          // L*B rows
#define LKK  1025
#define OUTOFF 8388608     // MR*DM floats, start of attn region in d_out
#define VPADF 24           // front pad rows of vbuf (covers shift -3..-1)

#define GB2 256            // gemm compute blocks (32 m-tiles x 8 n-tiles)
#define FBG 512            // extra fill blocks appended to each gemm grid
#define CHUNK 8192         // float4 per work-steal fill chunk (128 KB)
#define SCR4 2366464       // scratch float4s: (vbuf+valb+Wvb+Wob)=37,863,424 B
#define MID4 9580032       // SCR4 + (END4-SCR4)/2
#define END4 16793600      // attn total float4

typedef short bf16x8 __attribute__((ext_vector_type(8)));
typedef float f32x4  __attribute__((ext_vector_type(4)));
typedef unsigned short u16;
typedef u16 u16x8 __attribute__((ext_vector_type(8)));

__device__ __forceinline__ u16 f2bf(float f) {
  union { float f; unsigned u; } v; v.f = f;
  return (u16)((v.u + 0x7fffu + ((v.u >> 16) & 1u)) >> 16);  // RNE
}

__device__ __forceinline__ void gl_lds16(const u16* g, u16* l) {
  __builtin_amdgcn_global_load_lds((const __attribute__((address_space(1))) void*)g,
                                   (__attribute__((address_space(3))) void*)l,
                                   16, 0, 0);
}

// attn flat layout: [hb(64)][l(1024)][t(1025)]. One float4 of {0,1}.
__device__ __forceinline__ f32x4 onehot4(int i) {
  unsigned xf = (unsigned)i << 2;                       // linear float index
  unsigned row0 = (unsigned)(((unsigned long long)xf * 4290777085ULL) >> 42);
  int t0 = (int)(xf - row0 * 1025u);
  f32x4 v;
#pragma unroll
  for (int c = 0; c < 4; c++) {
    int tc = t0 + c;
    unsigned rc = row0 + ((tc >= 1025) ? 1u : 0u);
    tc -= (tc >= 1025) ? 1025 : 0;
    int h = (int)(rc >> 13);
    int l = (int)(rc & 1023u);
    int j = l + h - 3;
    int hot = ((unsigned)j <= 1024u) ? j : 1024;
    v[c] = (tc == hot) ? 1.0f : 0.0f;
  }
  return v;
}

// Work-stealing fill: blocks grab 128KB chunks until range [start,end) done.
// Late-arriving blocks exit immediately -> zero serialized tail.
__device__ __forceinline__ void fill_steal(unsigned* __restrict__ ctr,
                                           int start, int end,
                                           f32x4* __restrict__ attn4) {
  __shared__ int sbase;
  for (;;) {
    __syncthreads();
    if (threadIdx.x == 0) sbase = (int)atomicAdd(ctr, 1u);
    __syncthreads();
    int i0 = start + sbase * CHUNK;
    if (i0 >= end) return;
    int lim = (i0 + CHUNK < end) ? (i0 + CHUNK) : end;
    int i = i0 + (int)threadIdx.x;
#pragma unroll
    for (int r = 0; r < CHUNK / 512; ++r, i += 512)
      if (i < lim) __builtin_nontemporal_store(onehot4(i), attn4 + i);
  }
}

// XCD-friendly tile mapping for 256 blocks (32 m-tiles x 8 n-tiles):
// XCD = b%8 sees mt in {4x..4x+3} (1024 A rows, 2MB) x all 8 nt (B 2MB) -> 4MB/L2.
__device__ __forceinline__ void tile_of(int b, int& m0, int& n0) {
  int mt = (b & 7) * 4 + ((b >> 3) & 3);
  int nt = b >> 5;
  m0 = mt * 256; n0 = nt * 128;
}

// Convert value/Wv/Wo f32->bf16, zero vbuf pad rows, zero fill counters.
__global__ __launch_bounds__(256) void convert_k(const float* __restrict__ value,
                                                 const float* __restrict__ Wv,
                                                 const float* __restrict__ Wo,
                                                 u16* __restrict__ valb,
                                                 u16* __restrict__ Wvb,
                                                 u16* __restrict__ Wob,
                                                 u16* __restrict__ vbuf,
                                                 unsigned* __restrict__ ctr) {
  if (blockIdx.x == 0 && threadIdx.x < 2) ctr[threadIdx.x] = 0u;
  size_t c = (size_t)blockIdx.x * 256 + threadIdx.x;
  const size_t C1 = 1048576;            // value: 8388608/8
  const size_t C2 = C1 + 131072;        // + Wv
  const size_t C3 = C2 + 131072;        // + Wo = 1310720
  const size_t C4 = C3 + 7168;          // + pad rows (24+32 rows)
  if (c < C3) {
    const float* s; u16* d; size_t off;
    if (c < C1)      { s = value; d = valb; off = c * 8; }
    else if (c < C2) { s = Wv;    d = Wvb;  off = (c - C1) * 8; }
    else             { s = Wo;    d = Wob;  off = (c - C2) * 8; }
    float4 a = *(const float4*)(s + off);
    float4 b = *(const float4*)(s + off + 4);
    u16x8 p;
    p[0]=f2bf(a.x); p[1]=f2bf(a.y); p[2]=f2bf(a.z); p[3]=f2bf(a.w);
    p[4]=f2bf(b.x); p[5]=f2bf(b.y); p[6]=f2bf(b.z); p[7]=f2bf(b.w);
    *(u16x8*)(d + off) = p;
  } else if (c < C4) {
    size_t j = c - C3;
    u16x8 z = {0,0,0,0,0,0,0,0};
    if (j < 3072) *(u16x8*)(vbuf + j * 8) = z;                              // front 24 rows
    else *(u16x8*)(vbuf + (size_t)8216 * DM + (j - 3072) * 8) = z;          // back 32 rows
  }
}

// K-loop body: 8 ds_read_b128 frags + 16 MFMA per wave (2:1 MFMA:ds_read).
// LDS frag layout per 256x32 A tile: addr(row,kq)=(row>>4)*512+(row&15)*32+kq*8
// -> quarter-wave b128 groups read 256B contiguous (2-way = conflict-free).
#define GEMM_COMPUTE \
  { bf16x8 af[4], bfr[4]; \
    _Pragma("unroll") for (int i2 = 0; i2 < 4; i2++) \
      af[i2] = *(const bf16x8*)(smem + rO + ((wm >> 4) + i2) * 512 + lr * 32 + kq8); \
    _Pragma("unroll") for (int j2 = 0; j2 < 4; j2++) \
      bfr[j2] = *(const bf16x8*)(smem + rO + 8192 + ((wn >> 4) + j2) * 512 + lr * 32 + kq8); \
    __builtin_amdgcn_s_setprio(1); \
    _Pragma("unroll") for (int i2 = 0; i2 < 4; i2++) \
      _Pragma("unroll") for (int j2 = 0; j2 < 4; j2++) \
        acc[i2][j2] = __builtin_amdgcn_mfma_f32_16x16x32_bf16(af[i2], bfr[j2], acc[i2][j2], 0, 0, 0); \
    __builtin_amdgcn_s_setprio(0); }

#define PIPE_WAIT3 \
  asm volatile("s_waitcnt vmcnt(3)" ::: "memory"); \
  __builtin_amdgcn_s_barrier(); \
  __builtin_amdgcn_sched_barrier(0);

#define PIPE_WAIT0 \
  asm volatile("s_waitcnt vmcnt(0)" ::: "memory"); \
  __builtin_amdgcn_s_barrier(); \
  __builtin_amdgcn_sched_barrier(0);

#define PIPE_ROT { int tmp = rO; rO = pO; pO = sO; sO = tmp; }

// GEMM1: vproj[m][n] = sum_k valb[m][k]*Wvb[n][k] + bv[n] -> bf16 rows +VPADF.
// 256x128 tile, 8 waves of 64x64 (acc 4x4), BK=32, 3-buffer ring, depth-2
// counted vmcnt (3 loads/stage: A-lo, A-hi, B). Safety: each wave drains its
// own stage before the barrier; stage target buffer's last readers finished
// before the previous barrier. Blocks >= GB2 (and finished compute blocks)
// work-steal the attn fill of [SCR4, MID4).
__global__ __launch_bounds__(512, 4) void gemm1_k(const u16* __restrict__ valb,
                                                  const u16* __restrict__ Wvb,
                                                  const float* __restrict__ bv,
                                                  u16* __restrict__ vbuf,
                                                  f32x4* __restrict__ attn4,
                                                  unsigned* __restrict__ ctr) {
  __shared__ __align__(16) u16 smem[36864];   // 72 KB: 3 x (A 16KB + B 8KB); epilogue 66KB
  if (blockIdx.x >= GB2) { fill_steal(ctr, SCR4, MID4, attn4); return; }
  int m0, n0; tile_of(blockIdx.x, m0, n0);
  int t = threadIdx.x, lane = t & 63, wave = t >> 6;
  int wm = (wave >> 1) * 64, wn = (wave & 1) * 64;
  int srow = wave * 16 + (lane >> 2);         // staging row within 128-row half
  int ko = (lane & 3) * 8;                    // staging k offset
  int ldA0 = wave * 512;                      // LDS u16 offsets (wave-uniform)
  int ldA1 = (8 + wave) * 512;
  int ldB  = 8192 + wave * 512;
  int lr = lane & 15, kq8 = (lane >> 4) * 8;  // frag indices
  f32x4 z = {0.f, 0.f, 0.f, 0.f};
  f32x4 acc[4][4];
#pragma unroll
  for (int i = 0; i < 4; i++)
#pragma unroll
    for (int j = 0; j < 4; j++) acc[i][j] = z;

  const u16* Ab0 = valb + (size_t)(m0 + srow) * DM + ko;
  const u16* Ab1 = valb + (size_t)(m0 + 128 + srow) * DM + ko;
  const u16* Bb  = Wvb  + (size_t)(n0 + srow) * DM + ko;
#define STAGE1(koff, off) \
  gl_lds16(Ab0 + (koff), smem + (off) + ldA0); \
  gl_lds16(Ab1 + (koff), smem + (off) + ldA1); \
  gl_lds16(Bb  + (koff), smem + (off) + ldB);

  STAGE1(0, 0);
  STAGE1(32, 12288);
  int rO = 0, pO = 12288, sO = 24576;
  for (int kt = 0; kt < 30; ++kt) {
    PIPE_WAIT3;
    STAGE1((kt + 2) * 32, sO);
    GEMM_COMPUTE;
    PIPE_ROT;
  }
  PIPE_WAIT3;
  GEMM_COMPUTE;
  PIPE_ROT;
  PIPE_WAIT0;
  GEMM_COMPUTE;
  __syncthreads();

  // scatter acc -> LDS (bf16, padded stride 132), then coalesced u16x8 stores
  int q = lane >> 4, col = lane & 15;
#pragma unroll
  for (int j = 0; j < 4; j++) {
    int nl = wn + j * 16 + col;
    float bvn = bv[n0 + nl];
#pragma unroll
    for (int i = 0; i < 4; i++) {
      int ml = wm + i * 16 + q * 4;
#pragma unroll
      for (int r = 0; r < 4; r++)
        smem[(ml + r) * 132 + nl] = f2bf(acc[i][j][r] + bvn);
    }
  }
  __syncthreads();
  int cc = (t & 15) * 8;
  int rbase = (t >> 4) * 8;
#pragma unroll
  for (int s = 0; s < 8; s++) {
    int row = rbase + s;
    u16x8 v = *(const u16x8*)(smem + row * 132 + cc);
    *(u16x8*)(vbuf + (size_t)(m0 + row + VPADF) * DM + n0 + cc) = v;
  }
  fill_steal(ctr, SCR4, MID4, attn4);
#undef STAGE1
}

// GEMM2: x[m][n] = sum_k gather(vproj)[m][k]*Wob[n][k] + bo[n] + query[m][n]
// gather = per-head row shift (h-3)*8 (B=8 inner), absorbed via vbuf pad rows.
// Same 256x128 ring pipeline. Fill range: [MID4, END4).
__global__ __launch_bounds__(512, 4) void gemm2_k(const u16* __restrict__ vbuf,
                                                  const u16* __restrict__ Wob,
                                                  const float* __restrict__ bo,
                                                  const float* __restrict__ query,
                                                  float* __restrict__ xo,
                                                  f32x4* __restrict__ attn4,
                                                  unsigned* __restrict__ ctr) {
  __shared__ __align__(16) u16 smem[36864];   // 72 KB ring
  if (blockIdx.x >= GB2) { fill_steal(ctr, MID4, END4, attn4); return; }
  int m0, n0; tile_of(blockIdx.x, m0, n0);
  int t = threadIdx.x, lane = t & 63, wave = t >> 6;
  int wm = (wave >> 1) * 64, wn = (wave & 1) * 64;
  int srow = wave * 16 + (lane >> 2);
  int ko = (lane & 3) * 8;
  int ldA0 = wave * 512;
  int ldA1 = (8 + wave) * 512;
  int ldB  = 8192 + wave * 512;
  int lr = lane & 15, kq8 = (lane >> 4) * 8;
  f32x4 z = {0.f, 0.f, 0.f, 0.f};
  f32x4 acc[4][4];
#pragma unroll
  for (int i = 0; i < 4; i++)
#pragma unroll
    for (int j = 0; j < 4; j++) acc[i][j] = z;

  const u16* Ab0 = vbuf + (size_t)(m0 + srow + VPADF) * DM + ko;
  const u16* Ab1 = vbuf + (size_t)(m0 + 128 + srow + VPADF) * DM + ko;
  const u16* Bb  = Wob  + (size_t)(n0 + srow) * DM + ko;
  // A source for k-block kb: head h = kb>>2, row shift (h-3)*8 (pads zeroed)
#define STAGE2(kb, off) { \
  ptrdiff_t ao = (ptrdiff_t)((((kb) >> 2) - 3) * 8) * DM + (kb) * 32; \
  gl_lds16(Ab0 + ao, smem + (off) + ldA0); \
  gl_lds16(Ab1 + ao, smem + (off) + ldA1); \
  gl_lds16(Bb + (kb) * 32, smem + (off) + ldB); }

  STAGE2(0, 0);
  STAGE2(1, 12288);
  int rO = 0, pO = 12288, sO = 24576;
  for (int kt = 0; kt < 30; ++kt) {
    PIPE_WAIT3;
    STAGE2(kt + 2, sO);
    GEMM_COMPUTE;
    PIPE_ROT;
  }
  PIPE_WAIT3;
  GEMM_COMPUTE;
  PIPE_ROT;
  PIPE_WAIT0;
  GEMM_COMPUTE;

  int q = lane >> 4, col = lane & 15;
#pragma unroll
  for (int j = 0; j < 4; j++) {
    int n = n0 + wn + j * 16 + col;
    float bon = bo[n];
#pragma unroll
    for (int i = 0; i < 4; i++) {
      int mb = m0 + wm + i * 16 + q * 4;
#pragma unroll
      for (int r = 0; r < 4; r++) {
        size_t idx = (size_t)(mb + r) * DM + n;
        xo[idx] = acc[i][j][r] + bon + query[idx];
      }
    }
  }
  fill_steal(ctr, MID4, END4, attn4);
#undef STAGE2
}

// Fused LayerNorm + scratch-region attn fill.
// Blocks 0..2047: in-place LN over rows of x (one wave per row).
// Blocks 2048..3071: fill attn[0,SCR4) (the scratch region, now dead).
__global__ __launch_bounds__(256) void lnfill_k(float* __restrict__ x,
                                                const float* __restrict__ gamma,
                                                const float* __restrict__ beta,
                                                f32x4* __restrict__ attn4) {
  int blk = blockIdx.x;
  if (blk < 2048) {
    int lane = threadIdx.x & 63, wave = threadIdx.x >> 6;
    size_t row = (size_t)blk * 4 + wave;
    float4* p = (float4*)(x + row * DM);
    float4 v[4];
    float s = 0.f, ss = 0.f;
#pragma unroll
    for (int i = 0; i < 4; i++) {
      v[i] = p[i * 64 + lane];
      s  += v[i].x + v[i].y + v[i].z + v[i].w;
      ss += v[i].x * v[i].x + v[i].y * v[i].y + v[i].z * v[i].z + v[i].w * v[i].w;
    }
#pragma unroll
    for (int o = 32; o > 0; o >>= 1) {
      s  += __shfl_xor(s, o);
      ss += __shfl_xor(ss, o);
    }
    float mu = s * (1.0f / 1024.0f);
    float var = ss * (1.0f / 1024.0f) - mu * mu;
    float rstd = rsqrtf(var + 1e-5f);
    const float4* g4 = (const float4*)gamma;
    const float4* b4 = (const float4*)beta;
#pragma unroll
    for (int i = 0; i < 4; i++) {
      float4 g = g4[i * 64 + lane], bb = b4[i * 64 + lane];
      float4 o;
      o.x = (v[i].x - mu) * rstd * g.x + bb.x;
      o.y = (v[i].y - mu) * rstd * g.y + bb.y;
      o.z = (v[i].z - mu) * rstd * g.z + bb.z;
      o.w = (v[i].w - mu) * rstd * g.w + bb.w;
      p[i * 64 + lane] = o;
    }
  } else {
    int i = (blk - 2048) * 256 + (int)threadIdx.x;
    const int stride = 1024 * 256;
    for (; i < SCR4; i += stride)
      __builtin_nontemporal_store(onehot4(i), attn4 + i);
  }
}

extern "C" void kernel_launch(void* const* d_in, const int* in_sizes, int n_in,
                              void* d_out, int out_size, void* d_ws, size_t ws_size,
                              hipStream_t stream) {
  const float* query = (const float*)d_in[0];
  // d_in[1] key, d_in[3..6] Wq/bq/Wk/bk: dead code (scores overwritten by bias)
  const float* value = (const float*)d_in[2];
  const float* Wv    = (const float*)d_in[7];
  const float* bv    = (const float*)d_in[8];
  const float* Wo    = (const float*)d_in[9];
  const float* bo    = (const float*)d_in[10];
  const float* gamma = (const float*)d_in[11];
  const float* beta  = (const float*)d_in[12];

  float* out  = (float*)d_out;
  float* attn = out + OUTOFF;
  // Scratch lives inside the attn region (268.7 MB). attn fill is split:
  // [SCR4,MID4) stolen during gemm1, [MID4,END4) during gemm2 (work-steal,
  // no tail), [0,SCR4) (scratch) last, after gemm2 consumed vbuf.
  char* scr = (char*)attn;
  u16* vbuf = (u16*)scr;                              // 8248*1024*2 = 16,891,904 B
  u16* valb = (u16*)(scr + 16891904);                 // 16,777,216 B
  u16* Wvb  = (u16*)(scr + 33669120);                 //  2,097,152 B
  u16* Wob  = (u16*)(scr + 35766272);                 //  2,097,152 B
  unsigned* ctr = (unsigned*)d_ws;                    // [0]=gemm1 fill, [1]=gemm2 fill

  convert_k<<<5148, 256, 0, stream>>>(value, Wv, Wo, valb, Wvb, Wob, vbuf, ctr);
  gemm1_k<<<GB2 + FBG, 512, 0, stream>>>(valb, Wvb, bv, vbuf, (f32x4*)attn, ctr);
  gemm2_k<<<GB2 + FBG, 512, 0, stream>>>(vbuf, Wob, bo, query, out, (f32x4*)attn, ctr + 1);
  lnfill_k<<<3072, 256, 0, stream>>>(out, gamma, beta, (f32x4*)attn);
}